// Round 4
// baseline (150.024 us; speedup 1.0000x reference)
//
#include <hip/hip_runtime.h>

typedef float f32x4 __attribute__((ext_vector_type(4)));

__global__ __launch_bounds__(256) void ToneMapping_kernel(
    const float* __restrict__ x,
    const float* __restrict__ widths,
    const float* __restrict__ heights,
    const float* __restrict__ slopes,
    float* __restrict__ out,
    long long n4, long long n)
{
    // No LDS, no barrier: every wave computes the 5-bin parameter table in
    // uniform registers (amortized over ~24 grid-stride iterations), and each
    // element selects its bin's params via a 4-step v_cndmask cascade.
    //
    // Per bin, fold the whole spline into one rational quadratic in xf:
    //   t = (xf-xl)*iw;  num = (sl-2)t^2 + 2t;  den = s*t^2 + (2s-4)t + 2
    //   y = yl + dy*num/den = P(xf)/Q(xf)
    float e0, e1, e2, e3;
    float P2[5], P1[5], P0[5], Q2[5], Q1[5], Q0[5];
    {
        float edges[4];
        float c = 0.0f;
        #pragma unroll
        for (int i = 0; i < 5; ++i) {
            float w  = widths[i];
            float xl = c;                       // widths_cumsum[i]
            c = c + w;                          // bin_edges[i] (f32 cumsum order)
            if (i < 4) edges[i] = c;
            float iw = 1.0f / (w + 1e-8f);      // x_high-x_low == w to ~1ulp
            float yl = heights[i], yh = heights[i + 1];
            float dy = yh - yl;
            float sl = slopes[i],  sh = slopes[i + 1];
            float ss = sl + sh;
            // coefficients in u = xf - xl
            float a2 = (sl - 2.0f) * iw * iw;   // num u^2
            float a1 = 2.0f * iw;               // num u^1
            float b2 = ss * iw * iw;            // den u^2
            float b1 = (2.0f * ss - 4.0f) * iw; // den u^1  (den u^0 = 2)
            // y = (yl*den + dy*num)/den ; expand u = xf - xl into xf-polynomials
            float cc2 = fmaf(dy, a2, yl * b2);
            float cc1 = fmaf(dy, a1, yl * b1);
            float cc0 = 2.0f * yl;
            P2[i] = cc2;
            P1[i] = cc1 - 2.0f * cc2 * xl;
            P0[i] = fmaf(fmaf(cc2, xl, -cc1), xl, cc0);
            Q2[i] = b2;
            Q1[i] = b1 - 2.0f * b2 * xl;
            Q0[i] = fmaf(fmaf(b2, xl, -b1), xl, 2.0f);
        }
        e0 = edges[0]; e1 = edges[1]; e2 = edges[2]; e3 = edges[3];
    }

    const f32x4* __restrict__ x4 = (const f32x4*)x;
    f32x4* __restrict__ o4 = (f32x4*)out;

    auto eval1 = [&](float xin) -> float {
        float xf = fminf(fmaxf(xin, 0.0f), 1.0f);
        // searchsorted(edges, xf, 'left') clipped == cascade over e0..e3
        bool g0 = e0 < xf, g1 = e1 < xf, g2 = e2 < xf, g3 = e3 < xf;
        #define SEL(A) (g3 ? A[4] : (g2 ? A[3] : (g1 ? A[2] : (g0 ? A[1] : A[0]))))
        float p2 = SEL(P2), p1 = SEL(P1), p0 = SEL(P0);
        float q2 = SEL(Q2), q1 = SEL(Q1), q0 = SEL(Q0);
        #undef SEL
        float Pv = fmaf(xf, fmaf(xf, p2, p1), p0);   // Horner
        float Qv = fmaf(xf, fmaf(xf, q2, q1), q0);
        return Pv * __builtin_amdgcn_rcpf(Qv);
    };

    long long tid    = (long long)blockIdx.x * blockDim.x + threadIdx.x;
    long long stride = (long long)gridDim.x * blockDim.x;

    for (long long i = tid; i < n4; i += stride) {
        f32x4 v = x4[i];
        f32x4 r;
        r.x = eval1(v.x);
        r.y = eval1(v.y);
        r.z = eval1(v.z);
        r.w = eval1(v.w);
        o4[i] = r;
    }

    // Scalar tail (n % 4 != 0) — not hit for this shape.
    long long ts = n4 * 4;
    for (long long j = ts + tid; j < n; j += stride)
        out[j] = eval1(x[j]);
}

extern "C" void kernel_launch(void* const* d_in, const int* in_sizes, int n_in,
                              void* d_out, int out_size, void* d_ws, size_t ws_size,
                              hipStream_t stream) {
    const float* x       = (const float*)d_in[0];
    const float* widths  = (const float*)d_in[1];
    const float* heights = (const float*)d_in[2];
    const float* slopes  = (const float*)d_in[3];
    float* out = (float*)d_out;

    long long n  = (long long)in_sizes[0];
    long long n4 = n / 4;

    const int block = 256;
    long long want = (n4 + block - 1) / block;
    int grid = (int)(want < 2048 ? (want > 0 ? want : 1) : 2048);

    ToneMapping_kernel<<<grid, block, 0, stream>>>(x, widths, heights, slopes, out, n4, n);
}